// Round 1
// baseline (489.951 us; speedup 1.0000x reference)
//
#include <hip/hip_runtime.h>
#include <cstdint>

#define NUM_USERS 50000
#define NUM_ITEMS 40000
#define EMB 64
#define NNZ_E 2000000
#define BATCH 1024
#define H2 128
#define TM 128
#define TN 128
#define NCH 313   // ceil(40000/128)

// ---------------- init: map=INT_MAX, hb=0, scal=0 ----------------
__global__ void k_init(int* __restrict__ map, float* __restrict__ hb, float* __restrict__ scal) {
    int t = blockIdx.x * blockDim.x + threadIdx.x;
    if (t < NUM_USERS) map[t] = 0x7fffffff;
    if (t < BATCH * H2) hb[t] = 0.f;
    if (t < 2) scal[t] = 0.f;
}

// ---------------- mark batch users with first-occurrence slot ----------------
__global__ void k_map(const int* __restrict__ user, int* __restrict__ map) {
    int i = blockIdx.x * blockDim.x + threadIdx.x;
    if (i < BATCH) atomicMin(&map[user[i]], i);
}

// ---------------- transpose Wp (40000x64) -> WpT (64x40000) ----------------
__global__ __launch_bounds__(256) void k_wpt(const float* __restrict__ Wp, float* __restrict__ WpT) {
    __shared__ float t[64][65];
    const int tid = threadIdx.x;
    const int jb = blockIdx.x * 64;
    for (int idx = tid; idx < 4096; idx += 256) {
        int jl = idx >> 6, kl = idx & 63;
        t[jl][kl] = Wp[(size_t)(jb + jl) * EMB + kl];
    }
    __syncthreads();
    for (int idx = tid; idx < 4096; idx += 256) {
        int kl = idx >> 6, jl = idx & 63;
        WpT[(size_t)kl * NUM_ITEMS + jb + jl] = t[jl][kl];
    }
}

// ---------------- edge accumulate: hb[slot][0..127] += v * Wq[:,c] ----------------
__global__ __launch_bounds__(256) void k_edges(const int* __restrict__ rows,
                                               const int* __restrict__ cols,
                                               const float* __restrict__ vals,
                                               const int* __restrict__ map,
                                               const float* __restrict__ Wq,
                                               float* __restrict__ hb) {
    const int e = blockIdx.x * 256 + threadIdx.x;
    const int lane = threadIdx.x & 63;
    int slot = 0x7fffffff; int c = 0; float v = 0.f;
    if (e < NNZ_E) slot = map[rows[e]];
    bool f = (slot != 0x7fffffff);
    if (f) { c = cols[e]; v = vals[e]; }
    unsigned long long mb = __ballot(f);
    while (mb) {
        int src = __ffsll(mb) - 1;
        mb &= mb - 1;
        int   sl = __shfl(slot, src);
        int   cc = __shfl(c, src);
        float vv = __shfl(v, src);
        atomicAdd(&hb[sl * H2 + lane],      vv * Wq[(size_t)lane * NUM_ITEMS + cc]);
        atomicAdd(&hb[sl * H2 + 64 + lane], vv * Wq[(size_t)(lane + 64) * NUM_ITEMS + cc]);
    }
}

// ---------------- z + KL: one block (64 threads) per batch row ----------------
__global__ __launch_bounds__(64) void k_z(const float* __restrict__ hb,
                                          const float* __restrict__ bq,
                                          const float* __restrict__ eps,
                                          const int* __restrict__ user,
                                          const int* __restrict__ map,
                                          float* __restrict__ zbT,
                                          float* __restrict__ scal) {
    const int i = blockIdx.x;
    const int lane = threadIdx.x;
    const int u = user[i];
    const int slot = map[u];
    float mu = hb[slot * H2 + lane]      + bq[lane];
    float lv = hb[slot * H2 + 64 + lane] + bq[64 + lane];
    float z = mu + eps[(size_t)u * EMB + lane] * __expf(0.5f * lv);
    zbT[(size_t)lane * BATCH + i] = z;
    float kl = 1.0f + lv - mu * mu - __expf(lv);
    #pragma unroll
    for (int off = 32; off; off >>= 1) kl += __shfl_down(kl, off);
    if (lane == 0) atomicAdd(&scal[1], kl);
}

// ---------------- fused GEMM + online-softmax partials ----------------
// grid (NCH, 8); 256 threads; block tile 128 rows x 128 cols; K=64 resident
__global__ __launch_bounds__(256) void k_gemm(const float* __restrict__ zbT,
                                              const float* __restrict__ WpT,
                                              const float* __restrict__ bp,
                                              const float* __restrict__ x,
                                              float* __restrict__ part) {
    __shared__ float sZ[64][TM];
    __shared__ float sW[64][TN];
    const int tid = threadIdx.x;
    const int tx = tid & 15, ty = tid >> 4;
    const int jbase = blockIdx.x * TN;
    const int ibase = blockIdx.y * TM;

    for (int idx = tid; idx < 64 * TM / 4; idx += 256) {
        int k = idx >> 5; int i4 = (idx & 31) << 2;
        *(float4*)&sZ[k][i4] = *(const float4*)&zbT[(size_t)k * BATCH + ibase + i4];
        int j = jbase + i4;
        float4 w = make_float4(0.f, 0.f, 0.f, 0.f);
        if (j < NUM_ITEMS) w = *(const float4*)&WpT[(size_t)k * NUM_ITEMS + j];
        *(float4*)&sW[k][i4] = w;
    }
    __syncthreads();

    float acc[8][8];
    #pragma unroll
    for (int a = 0; a < 8; a++)
        #pragma unroll
        for (int b = 0; b < 8; b++) acc[a][b] = 0.f;

    #pragma unroll 4
    for (int k = 0; k < 64; k++) {
        float4 z0 = *(const float4*)&sZ[k][ty * 8];
        float4 z1 = *(const float4*)&sZ[k][ty * 8 + 4];
        float4 w0 = *(const float4*)&sW[k][tx * 8];
        float4 w1 = *(const float4*)&sW[k][tx * 8 + 4];
        float zr[8] = {z0.x, z0.y, z0.z, z0.w, z1.x, z1.y, z1.z, z1.w};
        float wr[8] = {w0.x, w0.y, w0.z, w0.w, w1.x, w1.y, w1.z, w1.w};
        #pragma unroll
        for (int a = 0; a < 8; a++)
            #pragma unroll
            for (int b = 0; b < 8; b++)
                acc[a][b] = fmaf(zr[a], wr[b], acc[a][b]);
    }

    // epilogue: per-row (within this 128-col chunk) m, sumexp, dot(recon,x), sum(x)
    const int jb = jbase + tx * 8;
    const bool valid = (jb < NUM_ITEMS);   // 40000 % 8 == 0 -> group-uniform
    float bpv[8];
    if (valid) {
        float4 b0 = *(const float4*)&bp[jb];
        float4 b1 = *(const float4*)&bp[jb + 4];
        bpv[0]=b0.x; bpv[1]=b0.y; bpv[2]=b0.z; bpv[3]=b0.w;
        bpv[4]=b1.x; bpv[5]=b1.y; bpv[6]=b1.z; bpv[7]=b1.w;
    }
    float m[8], s[8], dx[8], sx[8];
    #pragma unroll
    for (int a = 0; a < 8; a++) {
        if (valid) {
            const int gi = ibase + ty * 8 + a;
            float r[8];
            #pragma unroll
            for (int b = 0; b < 8; b++) r[b] = acc[a][b] + bpv[b];
            float mm = r[0];
            #pragma unroll
            for (int b = 1; b < 8; b++) mm = fmaxf(mm, r[b]);
            float4 x0 = *(const float4*)&x[(size_t)gi * NUM_ITEMS + jb];
            float4 x1 = *(const float4*)&x[(size_t)gi * NUM_ITEMS + jb + 4];
            float xv[8] = {x0.x, x0.y, x0.z, x0.w, x1.x, x1.y, x1.z, x1.w};
            float ss = 0.f, dd = 0.f, xs = 0.f;
            #pragma unroll
            for (int b = 0; b < 8; b++) {
                ss += __expf(r[b] - mm);
                dd = fmaf(r[b], xv[b], dd);
                xs += xv[b];
            }
            m[a] = mm; s[a] = ss; dx[a] = dd; sx[a] = xs;
        } else {
            m[a] = -1e30f; s[a] = 0.f; dx[a] = 0.f; sx[a] = 0.f;
        }
    }
    // butterfly across the 16 tx lanes (same 8 rows)
    #pragma unroll
    for (int d = 1; d < 16; d <<= 1) {
        #pragma unroll
        for (int a = 0; a < 8; a++) {
            float m2  = __shfl_xor(m[a], d);
            float s2  = __shfl_xor(s[a], d);
            float dx2 = __shfl_xor(dx[a], d);
            float sx2 = __shfl_xor(sx[a], d);
            float M = fmaxf(m[a], m2);
            s[a] = s[a] * __expf(m[a] - M) + s2 * __expf(m2 - M);
            m[a] = M; dx[a] += dx2; sx[a] += sx2;
        }
    }
    if (tx == 0) {
        #pragma unroll
        for (int a = 0; a < 8; a++) {
            int row = ibase + ty * 8 + a;
            float4 p = make_float4(m[a], s[a], dx[a], sx[a]);
            *(float4*)&part[((size_t)blockIdx.x * BATCH + row) * 4] = p;
        }
    }
}

// ---------------- merge chunk partials -> row loss -> scalar ----------------
__global__ __launch_bounds__(64) void k_merge(const float* __restrict__ part, float* __restrict__ scal) {
    const int row = blockIdx.x * 64 + threadIdx.x;
    float M = -1e30f, S = 0.f, DX = 0.f, SX = 0.f;
    for (int c = 0; c < NCH; c++) {
        float4 p = *(const float4*)&part[((size_t)c * BATCH + row) * 4];
        float M2 = fmaxf(M, p.x);
        S = S * __expf(M - M2) + p.y * __expf(p.x - M2);
        M = M2; DX += p.z; SX += p.w;
    }
    float loss = DX - (M + logf(S)) * SX;
    #pragma unroll
    for (int off = 32; off; off >>= 1) loss += __shfl_down(loss, off);
    if (threadIdx.x == 0) atomicAdd(&scal[0], loss);
}

// ---------------- final ----------------
__global__ void k_final(const float* __restrict__ scal, float* __restrict__ out) {
    if (threadIdx.x == 0 && blockIdx.x == 0) {
        out[0] = -scal[0] * (1.0f / BATCH);
        out[1] = -0.5f * scal[1] * (1.0f / BATCH);
    }
}

extern "C" void kernel_launch(void* const* d_in, const int* in_sizes, int n_in,
                              void* d_out, int out_size, void* d_ws, size_t ws_size,
                              hipStream_t stream) {
    const float* graph_vals = (const float*)d_in[0];
    const float* Wq         = (const float*)d_in[1];
    const float* bq         = (const float*)d_in[2];
    const float* Wp         = (const float*)d_in[3];
    const float* bp         = (const float*)d_in[4];
    const float* x          = (const float*)d_in[5];
    const float* eps        = (const float*)d_in[6];
    const int*   graph_rows = (const int*)d_in[7];
    const int*   graph_cols = (const int*)d_in[8];
    const int*   user       = (const int*)d_in[9];
    float* out = (float*)d_out;

    char* ws = (char*)d_ws;
    // ws layout
    int*   map  = (int*)(ws + 0);                         // 50000 ints   (200,000 B)
    float* hb   = (float*)(ws + 200704);                  // 1024*128 f32 (524,288 B)
    float* zbT  = (float*)(ws + 200704 + 524288);         // 64*1024 f32  (262,144 B)
    float* WpT  = (float*)(ws + 987136);                  // 64*40000 f32 (10,240,000 B)
    float* part = (float*)(ws + 11227136);                // 313*1024*4 f32 (5,128,192 B)
    float* scal = (float*)(ws + 16355328);                // 2 f32

    k_init<<<512, 256, 0, stream>>>(map, hb, scal);
    k_map<<<4, 256, 0, stream>>>(user, map);
    k_wpt<<<625, 256, 0, stream>>>(Wp, WpT);
    k_edges<<<(NNZ_E + 255) / 256, 256, 0, stream>>>(graph_rows, graph_cols, graph_vals, map, Wq, hb);
    k_z<<<BATCH, 64, 0, stream>>>(hb, bq, eps, user, map, zbT, scal);
    dim3 g(NCH, BATCH / TM);
    k_gemm<<<g, 256, 0, stream>>>(zbT, WpT, bp, x, part);
    k_merge<<<BATCH / 64, 64, 0, stream>>>(part, scal);
    k_final<<<1, 64, 0, stream>>>(scal, out);
}

// Round 2
// 391.328 us; speedup vs baseline: 1.2520x; 1.2520x over previous
//
#include <hip/hip_runtime.h>
#include <cstdint>

#define NUM_USERS 50000
#define NUM_ITEMS 40000
#define EMB 64
#define NNZ_E 2000000
#define BATCH 1024
#define NCH 625            // 40000 / 64 column chunks (exact)
#define CAP 131072         // compact edge capacity (~40k expected)
#define INF_I 0x7fffffff

typedef __attribute__((ext_vector_type(8))) short short8;   // 8 x bf16 (4 VGPRs)
typedef __attribute__((ext_vector_type(4))) float float4v;  // MFMA C/D

__device__ __forceinline__ unsigned short f2bf(float f) {
    union { float f; unsigned u; } x; x.f = f;
    unsigned r = x.u + 0x7fffu + ((x.u >> 16) & 1u);
    return (unsigned short)(r >> 16);
}
__device__ __forceinline__ float bf2f(unsigned short s) {
    return __uint_as_float(((unsigned)s) << 16);
}

// ---------------- init: map=INF, cnt=0, scal=0 ----------------
__global__ void k_init(int* __restrict__ map, int* __restrict__ cnt, float* __restrict__ scal) {
    int t = blockIdx.x * blockDim.x + threadIdx.x;
    if (t < NUM_USERS) map[t] = INF_I;
    if (t < BATCH) cnt[t] = 0;
    if (t < 4) scal[t] = 0.f;
}

// ---------------- batch users -> first-occurrence slot ----------------
__global__ void k_map(const int* __restrict__ user, int* __restrict__ map) {
    int i = blockIdx.x * blockDim.x + threadIdx.x;
    if (i < BATCH) atomicMin(&map[user[i]], i);
}

// ---------------- fused prep: Wq transpose->bf16 | Wp cvt->bf16 | edge count ----------------
// grid: [0,1250) WqT tiles, [1250,3750) Wp cvt, [3750,11563) edge count
__global__ __launch_bounds__(256) void k_prep(const float* __restrict__ Wq,
                                              const float* __restrict__ Wp,
                                              const int* __restrict__ rows,
                                              const int* __restrict__ map,
                                              unsigned short* __restrict__ WqT,
                                              unsigned short* __restrict__ WpBf,
                                              int* __restrict__ cnt) {
    __shared__ float t[128][33];
    const int bid = blockIdx.x;
    const int tid = threadIdx.x;
    if (bid < 1250) {
        const int jb = bid * 32;
        for (int idx = tid; idx < 4096; idx += 256) {
            int d = idx >> 5, c = idx & 31;
            t[d][c] = Wq[(size_t)d * NUM_ITEMS + jb + c];
        }
        __syncthreads();
        for (int idx = tid; idx < 4096; idx += 256) {
            int j = idx >> 7, d = idx & 127;
            WqT[(size_t)(jb + j) * 128 + d] = f2bf(t[d][j]);
        }
    } else if (bid < 3750) {
        const int e0 = ((bid - 1250) * 256 + tid) * 4;
        float4 w = *(const float4*)&Wp[e0];
        ushort4 o;
        o.x = f2bf(w.x); o.y = f2bf(w.y); o.z = f2bf(w.z); o.w = f2bf(w.w);
        *(ushort4*)&WpBf[e0] = o;
    } else {
        const int e = (bid - 3750) * 256 + tid;
        if (e < NNZ_E) {
            int s = map[rows[e]];
            if (s != INF_I) atomicAdd(&cnt[s], 1);
        }
    }
}

// ---------------- exclusive scan of cnt -> off, cur ----------------
__global__ __launch_bounds__(1024) void k_scan(const int* __restrict__ cnt,
                                               int* __restrict__ off, int* __restrict__ cur) {
    __shared__ int s[1024];
    const int t = threadIdx.x;
    const int c = cnt[t];
    s[t] = c; __syncthreads();
    for (int d = 1; d < 1024; d <<= 1) {
        int v = (t >= d) ? s[t - d] : 0;
        __syncthreads();
        s[t] += v;
        __syncthreads();
    }
    int inc = s[t];
    off[t + 1] = inc;
    cur[t] = inc - c;
    if (t == 0) off[0] = 0;
}

// ---------------- scatter active edges to per-slot lists ----------------
__global__ __launch_bounds__(256) void k_scatter(const int* __restrict__ rows,
                                                 const int* __restrict__ cols,
                                                 const float* __restrict__ vals,
                                                 const int* __restrict__ map,
                                                 int* __restrict__ cur,
                                                 int2* __restrict__ compact) {
    const int e = blockIdx.x * 256 + threadIdx.x;
    if (e >= NNZ_E) return;
    int s = map[rows[e]];
    if (s == INF_I) return;
    int pos = atomicAdd(&cur[s], 1);
    if (pos < CAP) compact[pos] = make_int2(cols[e], __float_as_int(vals[e]));
}

// ---------------- per-row: h accumulate + z + KL; writes zbBf [1024][64] bf16 ----------------
__global__ __launch_bounds__(128) void k_hz(const int* __restrict__ user,
                                            const int* __restrict__ map,
                                            const int* __restrict__ off,
                                            const int2* __restrict__ compact,
                                            const unsigned short* __restrict__ WqT,
                                            const float* __restrict__ bq,
                                            const float* __restrict__ eps,
                                            unsigned short* __restrict__ zbBf,
                                            float* __restrict__ scal) {
    __shared__ float sh[128];
    const int i = blockIdx.x;
    const int tid = threadIdx.x;
    const int u = user[i];
    const int s = map[u];
    const int b = off[s], eN = off[s + 1];
    float acc = 0.f;
    int e = b;
    int2 cv = (e < eN) ? compact[e] : make_int2(0, 0);
    while (e < eN) {
        int2 nx = (e + 1 < eN) ? compact[e + 1] : make_int2(0, 0);
        float w = bf2f(WqT[(size_t)cv.x * 128 + tid]);
        acc = fmaf(__int_as_float(cv.y), w, acc);
        cv = nx; e++;
    }
    sh[tid] = acc + bq[tid];
    __syncthreads();
    if (tid < 64) {
        float mu = sh[tid];
        float lv = sh[tid + 64];
        float z = mu + eps[(size_t)u * EMB + tid] * __expf(0.5f * lv);
        zbBf[i * EMB + tid] = f2bf(z);
        float kl = 1.0f + lv - mu * mu - __expf(lv);
        #pragma unroll
        for (int o = 32; o; o >>= 1) kl += __shfl_down(kl, o);
        if (tid == 0) atomicAdd(&scal[1], kl);
    }
}

// ---------------- MFMA GEMM + fused online-softmax partials ----------------
// grid (625, 8), 256 thr = 4 waves; wave: 32 rows x 64 cols, no LDS
__global__ __launch_bounds__(256) void k_gemm(const unsigned short* __restrict__ zbBf,
                                              const unsigned short* __restrict__ WpBf,
                                              const float* __restrict__ bp,
                                              const float* __restrict__ x,
                                              float* __restrict__ part) {
    const int tid = threadIdx.x;
    const int wid = tid >> 6, lane = tid & 63;
    const int l15 = lane & 15, quad = lane >> 4;
    const int jb = blockIdx.x * 64;
    const int ibase = blockIdx.y * 128 + wid * 32;

    short8 af[2][2], bf[4][2];
    #pragma unroll
    for (int mt = 0; mt < 2; mt++) {
        const unsigned short* pa = zbBf + (size_t)(ibase + mt * 16 + l15) * EMB + quad * 8;
        af[mt][0] = *(const short8*)pa;
        af[mt][1] = *(const short8*)(pa + 32);
    }
    #pragma unroll
    for (int nt = 0; nt < 4; nt++) {
        const unsigned short* pb = WpBf + (size_t)(jb + nt * 16 + l15) * EMB + quad * 8;
        bf[nt][0] = *(const short8*)pb;
        bf[nt][1] = *(const short8*)(pb + 32);
    }
    float4v acc[2][4];
    #pragma unroll
    for (int mt = 0; mt < 2; mt++)
        #pragma unroll
        for (int nt = 0; nt < 4; nt++)
            acc[mt][nt] = (float4v){0.f, 0.f, 0.f, 0.f};
    #pragma unroll
    for (int kh = 0; kh < 2; kh++)
        #pragma unroll
        for (int mt = 0; mt < 2; mt++)
            #pragma unroll
            for (int nt = 0; nt < 4; nt++)
                acc[mt][nt] = __builtin_amdgcn_mfma_f32_16x16x32_bf16(
                    af[mt][kh], bf[nt][kh], acc[mt][nt], 0, 0, 0);

    float bpv[4];
    #pragma unroll
    for (int nt = 0; nt < 4; nt++) bpv[nt] = bp[jb + nt * 16 + l15];

    #pragma unroll
    for (int mt = 0; mt < 2; mt++) {
        #pragma unroll
        for (int r = 0; r < 4; r++) {
            const int gi = ibase + mt * 16 + quad * 4 + r;
            float v[4];
            #pragma unroll
            for (int nt = 0; nt < 4; nt++) v[nt] = acc[mt][nt][r] + bpv[nt];
            float mm = fmaxf(fmaxf(v[0], v[1]), fmaxf(v[2], v[3]));
            #pragma unroll
            for (int d = 1; d < 16; d <<= 1) mm = fmaxf(mm, __shfl_xor(mm, d));
            const float* xr = x + (size_t)gi * NUM_ITEMS + jb + l15;
            float s = 0.f, dx = 0.f, sx = 0.f;
            #pragma unroll
            for (int nt = 0; nt < 4; nt++) {
                float xv = xr[nt * 16];
                s += __expf(v[nt] - mm);
                dx = fmaf(v[nt], xv, dx);
                sx += xv;
            }
            #pragma unroll
            for (int d = 1; d < 16; d <<= 1) {
                s += __shfl_xor(s, d);
                dx += __shfl_xor(dx, d);
                sx += __shfl_xor(sx, d);
            }
            if (l15 == 0)
                *(float4*)&part[((size_t)gi * NCH + blockIdx.x) * 4] =
                    make_float4(mm, s, dx, sx);
        }
    }
}

// ---------------- merge chunk partials per row -> loss scalar ----------------
__global__ __launch_bounds__(64) void k_merge(const float* __restrict__ part,
                                              float* __restrict__ scal) {
    const int row = blockIdx.x;
    const int lane = threadIdx.x;
    float M = -1e30f, S = 0.f, DX = 0.f, SX = 0.f;
    for (int c = lane; c < NCH; c += 64) {
        float4 p = *(const float4*)&part[((size_t)row * NCH + c) * 4];
        float M2 = fmaxf(M, p.x);
        S = S * __expf(M - M2) + p.y * __expf(p.x - M2);
        M = M2; DX += p.z; SX += p.w;
    }
    #pragma unroll
    for (int d = 1; d < 64; d <<= 1) {
        float M2  = __shfl_xor(M, d);
        float S2  = __shfl_xor(S, d);
        float DX2 = __shfl_xor(DX, d);
        float SX2 = __shfl_xor(SX, d);
        float Mn = fmaxf(M, M2);
        S = S * __expf(M - Mn) + S2 * __expf(M2 - Mn);
        M = Mn; DX += DX2; SX += SX2;
    }
    if (lane == 0) {
        float loss = DX - (M + logf(S)) * SX;
        atomicAdd(&scal[0], loss);
    }
}

// ---------------- final ----------------
__global__ void k_final(const float* __restrict__ scal, float* __restrict__ out) {
    if (threadIdx.x == 0 && blockIdx.x == 0) {
        out[0] = -scal[0] * (1.0f / BATCH);
        out[1] = -0.5f * scal[1] * (1.0f / BATCH);
    }
}

extern "C" void kernel_launch(void* const* d_in, const int* in_sizes, int n_in,
                              void* d_out, int out_size, void* d_ws, size_t ws_size,
                              hipStream_t stream) {
    const float* Wq         = (const float*)d_in[1];
    const float* bq         = (const float*)d_in[2];
    const float* Wp         = (const float*)d_in[3];
    const float* bp         = (const float*)d_in[4];
    const float* x          = (const float*)d_in[5];
    const float* eps        = (const float*)d_in[6];
    const float* graph_vals = (const float*)d_in[0];
    const int*   graph_rows = (const int*)d_in[7];
    const int*   graph_cols = (const int*)d_in[8];
    const int*   user       = (const int*)d_in[9];
    float* out = (float*)d_out;

    char* ws = (char*)d_ws;
    int*            map     = (int*)(ws + 0);              // 200,000 B
    int*            cnt     = (int*)(ws + 200704);         // 4,096 B
    int*            off     = (int*)(ws + 204800);         // 4,100 -> 4,608 B
    int*            cur     = (int*)(ws + 209408);         // 4,096 B
    float*          scal    = (float*)(ws + 213504);       // 16 B
    int2*           compact = (int2*)(ws + 213520);        // 1,048,576 B
    unsigned short* zbBf    = (unsigned short*)(ws + 1262096);   // 131,072 B
    unsigned short* WpBf    = (unsigned short*)(ws + 1393168);   // 5,120,000 B
    unsigned short* WqT     = (unsigned short*)(ws + 6513168);   // 10,240,000 B
    float*          part    = (float*)(ws + 6513168);      // overlaid on WqT (dead after k_hz)

    k_init<<<196, 256, 0, stream>>>(map, cnt, scal);
    k_map<<<4, 256, 0, stream>>>(user, map);
    k_prep<<<11563, 256, 0, stream>>>(Wq, Wp, graph_rows, map, WqT, WpBf, cnt);
    k_scan<<<1, 1024, 0, stream>>>(cnt, off, cur);
    k_scatter<<<7813, 256, 0, stream>>>(graph_rows, graph_cols, graph_vals, map, cur, compact);
    k_hz<<<BATCH, 128, 0, stream>>>(user, map, off, compact, WqT, bq, eps, zbBf, scal);
    dim3 g(NCH, BATCH / 128);
    k_gemm<<<g, 256, 0, stream>>>(zbBf, WpBf, bp, x, part);
    k_merge<<<BATCH, 64, 0, stream>>>(part, scal);
    k_final<<<1, 64, 0, stream>>>(scal, out);
}